// Round 11
// baseline (500.422 us; speedup 1.0000x reference)
//
#include <hip/hip_runtime.h>
#include <hip/hip_bf16.h>

#define H_DIM 1024
#define I_DIM 2048
#define NE 8
#define NT 4096

typedef __bf16 bf16x8 __attribute__((ext_vector_type(8)));
typedef __bf16 bf16x4 __attribute__((ext_vector_type(4)));
typedef float f32x4 __attribute__((ext_vector_type(4)));

// 16B-chunk index within a [rows][8-chunk] LDS tile, XOR-swizzled (verified
// conflict-free R1-R10: SQ_LDS_BANK_CONFLICT == 0).
__device__ __forceinline__ int swzc(int r, int j) { return r * 8 + (j ^ (r & 7)); }

// async global->LDS, 16B per lane. LDS dest is wave-uniform base (HW adds lane*16).
__device__ __forceinline__ void gl16(const void* g, void* l) {
  __builtin_amdgcn_global_load_lds(
      (const __attribute__((address_space(1))) unsigned int*)g,
      (__attribute__((address_space(3))) unsigned int*)l, 16, 0, 0);
}

__device__ __forceinline__ bf16x8 cvt8(float4 a, float4 b) {
  bf16x8 r;
  r[0] = (__bf16)a.x; r[1] = (__bf16)a.y; r[2] = (__bf16)a.z; r[3] = (__bf16)a.w;
  r[4] = (__bf16)b.x; r[5] = (__bf16)b.y; r[6] = (__bf16)b.z; r[7] = (__bf16)b.w;
  return r;
}

// Router: sigmoid top-2 renorm + per-expert token lists; fuses x -> bf16 cast.
__global__ __launch_bounds__(256) void k_router(const float* __restrict__ x,
                                                const float* __restrict__ rw,
                                                const float* __restrict__ rbias,
                                                __bf16* __restrict__ xb,
                                                int* __restrict__ counts,
                                                int* __restrict__ list,
                                                int* __restrict__ tE,
                                                int* __restrict__ tP,
                                                float* __restrict__ tG) {
  int wv = threadIdx.x >> 6, lane = threadIdx.x & 63;
  int t = blockIdx.x * 4 + wv;
  float acc[NE];
#pragma unroll
  for (int e = 0; e < NE; e++) acc[e] = 0.f;
  const float4* xr = (const float4*)(x + (size_t)t * H_DIM);
  const float4* wr4 = (const float4*)rw;
  bf16x4* xo = (bf16x4*)xb + (size_t)t * (H_DIM / 4);
#pragma unroll
  for (int it = 0; it < 4; ++it) {
    int c = it * 64 + lane;
    float4 xv = xr[c];
    bf16x4 bv;
    bv[0] = (__bf16)xv.x; bv[1] = (__bf16)xv.y;
    bv[2] = (__bf16)xv.z; bv[3] = (__bf16)xv.w;
    xo[c] = bv;
#pragma unroll
    for (int e = 0; e < NE; e++) {
      float4 wv2 = wr4[e * (H_DIM / 4) + c];
      acc[e] += xv.x * wv2.x + xv.y * wv2.y + xv.z * wv2.z + xv.w * wv2.w;
    }
  }
#pragma unroll
  for (int e = 0; e < NE; e++) {
#pragma unroll
    for (int off = 32; off > 0; off >>= 1) acc[e] += __shfl_xor(acc[e], off, 64);
  }
  if (lane == 0) {
    float p[NE];
#pragma unroll
    for (int e = 0; e < NE; e++) p[e] = 1.f / (1.f + expf(-(acc[e] + rbias[e])));
    int e0 = 0;
#pragma unroll
    for (int e = 1; e < NE; e++) if (p[e] > p[e0]) e0 = e;
    int e1 = -1;
#pragma unroll
    for (int e = 0; e < NE; e++) if (e != e0 && (e1 < 0 || p[e] > p[e1])) e1 = e;
    float s = p[e0] + p[e1];
    float g0 = p[e0] / s, g1 = p[e1] / s;
    int p0 = atomicAdd(&counts[e0], 1);
    int p1 = atomicAdd(&counts[e1], 1);
    list[e0 * NT + p0] = t;
    list[e1 * NT + p1] = t;
    tE[t * 2] = e0; tE[t * 2 + 1] = e1;
    tP[t * 2] = p0; tP[t * 2 + 1] = p1;
    tG[t * 2] = g0; tG[t * 2 + 1] = g1;
  }
}

// ---------------------------------------------------------------------------
// Fused gate+up GEMM, m97 config: tile 128 token-rows x 64 i-cols x {g,u},
// BK=64, 4 waves (2x2), 64 KB dbuf LDS -> 2 blocks/CU.
// A (xb, bf16) staged via global_load_lds. B (wg/wu, *fp32*) reg-staged:
// issue float4 loads for kt+1 right after the barrier, MFMA on kt, then
// cvt8 + ds_write_b128 into buf^1 (issue-early / write-late; WAR-safe:
// buf^1's readers were fenced by the barrier at top of this iteration).
// LDS layout/content identical to the precast path (pre-swizzled source,
// linear LDS write), so fragment reads and epilogue are unchanged.
// ---------------------------------------------------------------------------
__global__ __launch_bounds__(256, 2) void k_upgate97(
    const __bf16* __restrict__ xb, const float* __restrict__ wg,
    const float* __restrict__ wu, const float* __restrict__ sgw,
    const float* __restrict__ suw, const int* __restrict__ counts,
    const int* __restrict__ list,
    __bf16* __restrict__ hs, __bf16* __restrict__ hr) {
  int z = blockIdx.z;
  int m0 = blockIdx.y * 128, n0 = blockIdx.x * 64;
  bool sh = (z == NE);
  int count, base = 0;
  const float *Bg, *Bu;
  if (sh) {
    count = NT; Bg = sgw; Bu = suw;
  } else {
    count = counts[z];
    if (m0 >= count) return;
    for (int e = 0; e < z; e++) base += counts[e];
    Bg = wg + (size_t)z * (I_DIM * H_DIM);
    Bu = wu + (size_t)z * (I_DIM * H_DIM);
  }

  __shared__ bf16x8 lds[4096];   // [2][A 1024 | B 1024] = 64 KB

  int tid = threadIdx.x, lane = tid & 63, w = tid >> 6;
  int wr = w >> 1, wc = w & 1;
  int fr = lane & 15, fs = lane >> 4;

  const bf16x8* a8 = (const bf16x8*)xb;

  const bf16x8* pA[4];
  const float4* pB4[4];
#pragma unroll
  for (int q = 0; q < 4; q++) {
    int c = q * 256 + tid;                  // chunk 0..1023 (128 rows x 8)
    int r = c >> 3, j = (c & 7) ^ (r & 7);  // pre-swizzled source chunk
    int gr = m0 + r;
    int tok = sh ? gr : ((gr < count) ? list[z * NT + gr] : list[z * NT]);
    pA[q] = a8 + (size_t)tok * (H_DIM / 8) + j;
    int G = r >> 6, gu = (r >> 5) & 1, cc = r & 31;
    const float* bb = gu ? Bu : Bg;
    pB4[q] = (const float4*)bb + (size_t)(n0 + G * 32 + cc) * (H_DIM / 4) + 2 * j;
  }

  f32x4 acc[4][4];
#pragma unroll
  for (int m = 0; m < 4; m++)
#pragma unroll
    for (int n = 0; n < 4; n++) acc[m][n] = (f32x4){0.f, 0.f, 0.f, 0.f};

  // prologue: stage tile 0 (A via gl16, B via reg-cvt)
  {
    bf16x8* dA = lds;
    bf16x8* dB = lds + 1024;
#pragma unroll
    for (int q = 0; q < 4; q++) gl16(pA[q], dA + q * 256 + w * 64);
    float4 va[4], vb[4];
#pragma unroll
    for (int q = 0; q < 4; q++) { va[q] = pB4[q][0]; vb[q] = pB4[q][1]; }
#pragma unroll
    for (int q = 0; q < 4; q++) dB[q * 256 + tid] = cvt8(va[q], vb[q]);
  }

  const int NK = H_DIM / 64;  // 16
  for (int kt = 0; kt < NK; ++kt) {
    __syncthreads();           // tile kt fully staged; WAR-fence for buf^1
    bool pf = (kt + 1 < NK);
    float4 va[4], vb[4];
    if (pf) {
      bf16x8* dA = lds + ((kt + 1) & 1) * 2048;
      int koA = (kt + 1) * 8;
#pragma unroll
      for (int q = 0; q < 4; q++) gl16(pA[q] + koA, dA + q * 256 + w * 64);
      int koB = (kt + 1) * 16;  // float4 units
#pragma unroll
      for (int q = 0; q < 4; q++) { va[q] = pB4[q][koB]; vb[q] = pB4[q][koB + 1]; }
    }
    const bf16x8* Ac = lds + (kt & 1) * 2048;
    const bf16x8* Bc = Ac + 1024;
#pragma unroll
    for (int ks = 0; ks < 2; ks++) {
      bf16x8 af[4], bfr[4];
#pragma unroll
      for (int mf = 0; mf < 4; mf++) af[mf] = Ac[swzc(wr * 64 + mf * 16 + fr, ks * 4 + fs)];
#pragma unroll
      for (int nf = 0; nf < 4; nf++) bfr[nf] = Bc[swzc(wc * 64 + nf * 16 + fr, ks * 4 + fs)];
      __builtin_amdgcn_s_setprio(1);
#pragma unroll
      for (int m = 0; m < 4; m++)
#pragma unroll
        for (int n = 0; n < 4; n++)
          acc[m][n] = __builtin_amdgcn_mfma_f32_16x16x32_bf16(af[m], bfr[n], acc[m][n], 0, 0, 0);
      __builtin_amdgcn_s_setprio(0);
    }
    if (pf) {                  // write-late: B of kt+1 into buf^1
      bf16x8* dB = lds + ((kt + 1) & 1) * 2048 + 1024;
#pragma unroll
      for (int q = 0; q < 4; q++) dB[q * 256 + tid] = cvt8(va[q], vb[q]);
    }
  }

  // epilogue: h = silu(g)*u; g = acc[m][np], u = acc[m][np+2]
#pragma unroll
  for (int m = 0; m < 4; m++)
#pragma unroll
    for (int np = 0; np < 2; np++)
#pragma unroll
      for (int q2 = 0; q2 < 4; q2++) {
        int row = wr * 64 + m * 16 + fs * 4 + q2;
        int col = n0 + wc * 32 + np * 16 + fr;
        float g = acc[m][np][q2], u = acc[m][np + 2][q2];
        float h = g * u / (1.f + expf(-g));
        __bf16 hb = (__bf16)h;
        int grow = m0 + row;
        if (sh) hs[(size_t)grow * I_DIM + col] = hb;
        else if (grow < count) hr[(size_t)(base + grow) * I_DIM + col] = hb;
      }
}

// ---------------------------------------------------------------------------
// Down GEMM, m97 config: 128x128 tile, BK=64, 4 waves (2x2), 64 KB dbuf LDS
// -> 2 blocks/CU. A (h, bf16) via gl16; B (wd, *fp32*) reg-staged cvt, same
// issue-early / write-late pipeline as k_upgate97.
// ---------------------------------------------------------------------------
__global__ __launch_bounds__(256, 2) void k_down97(
    const __bf16* __restrict__ hs, const __bf16* __restrict__ hr,
    const float* __restrict__ wd, const float* __restrict__ sdw,
    const int* __restrict__ counts,
    float* __restrict__ out, float* __restrict__ y) {
  int z = blockIdx.z;
  int m0 = blockIdx.y * 128, n0 = blockIdx.x * 128;
  bool sh = (z == NE);
  int count, base = 0;
  const float* B;
  const __bf16* A;
  if (sh) {
    count = NT; B = sdw; A = hs;
  } else {
    count = counts[z];
    if (m0 >= count) return;
    for (int e = 0; e < z; e++) base += counts[e];
    B = wd + (size_t)z * (H_DIM * I_DIM);
    A = hr + (size_t)base * I_DIM;
  }

  __shared__ bf16x8 lds[4096];   // [2][A 1024 | B 1024] = 64 KB

  int tid = threadIdx.x, lane = tid & 63, w = tid >> 6;
  int wr = w >> 1, wc = w & 1;
  int fr = lane & 15, fs = lane >> 4;

  const bf16x8* a8 = (const bf16x8*)A;

  const bf16x8* pA[4];
  const float4* pB4[4];
#pragma unroll
  for (int q = 0; q < 4; q++) {
    int c = q * 256 + tid;                  // chunk 0..1023 (128 rows x 8)
    int r = c >> 3, j = (c & 7) ^ (r & 7);
    int ra = m0 + r; if (ra >= count) ra = count - 1;
    pA[q] = a8 + (size_t)ra * (I_DIM / 8) + j;
    pB4[q] = (const float4*)B + (size_t)(n0 + r) * (I_DIM / 4) + 2 * j;
  }

  f32x4 acc[4][4];
#pragma unroll
  for (int m = 0; m < 4; m++)
#pragma unroll
    for (int n = 0; n < 4; n++) acc[m][n] = (f32x4){0.f, 0.f, 0.f, 0.f};

  // prologue: stage tile 0
  {
    bf16x8* dA = lds;
    bf16x8* dB = lds + 1024;
#pragma unroll
    for (int q = 0; q < 4; q++) gl16(pA[q], dA + q * 256 + w * 64);
    float4 va[4], vb[4];
#pragma unroll
    for (int q = 0; q < 4; q++) { va[q] = pB4[q][0]; vb[q] = pB4[q][1]; }
#pragma unroll
    for (int q = 0; q < 4; q++) dB[q * 256 + tid] = cvt8(va[q], vb[q]);
  }

  const int NK = I_DIM / 64;  // 32
  for (int kt = 0; kt < NK; ++kt) {
    __syncthreads();
    bool pf = (kt + 1 < NK);
    float4 va[4], vb[4];
    if (pf) {
      bf16x8* dA = lds + ((kt + 1) & 1) * 2048;
      int koA = (kt + 1) * 8;
#pragma unroll
      for (int q = 0; q < 4; q++) gl16(pA[q] + koA, dA + q * 256 + w * 64);
      int koB = (kt + 1) * 16;
#pragma unroll
      for (int q = 0; q < 4; q++) { va[q] = pB4[q][koB]; vb[q] = pB4[q][koB + 1]; }
    }
    const bf16x8* Ac = lds + (kt & 1) * 2048;
    const bf16x8* Bc = Ac + 1024;
#pragma unroll
    for (int ks = 0; ks < 2; ks++) {
      bf16x8 af[4], bfr[4];
#pragma unroll
      for (int mf = 0; mf < 4; mf++) af[mf] = Ac[swzc(wr * 64 + mf * 16 + fr, ks * 4 + fs)];
#pragma unroll
      for (int nf = 0; nf < 4; nf++) bfr[nf] = Bc[swzc(wc * 64 + nf * 16 + fr, ks * 4 + fs)];
      __builtin_amdgcn_s_setprio(1);
#pragma unroll
      for (int m = 0; m < 4; m++)
#pragma unroll
        for (int n = 0; n < 4; n++)
          acc[m][n] = __builtin_amdgcn_mfma_f32_16x16x32_bf16(af[m], bfr[n], acc[m][n], 0, 0, 0);
      __builtin_amdgcn_s_setprio(0);
    }
    if (pf) {
      bf16x8* dB = lds + ((kt + 1) & 1) * 2048 + 1024;
#pragma unroll
      for (int q = 0; q < 4; q++) dB[q * 256 + tid] = cvt8(va[q], vb[q]);
    }
  }

#pragma unroll
  for (int m = 0; m < 4; m++)
#pragma unroll
    for (int n = 0; n < 4; n++)
#pragma unroll
      for (int q2 = 0; q2 < 4; q2++) {
        int row = wr * 64 + m * 16 + fs * 4 + q2;
        int col = n0 + wc * 64 + n * 16 + fr;
        float v = acc[m][n][q2];
        int grow = m0 + row;
        if (sh) out[(size_t)grow * H_DIM + col] = v;
        else if (grow < count) y[(size_t)(base + grow) * H_DIM + col] = v;
      }
}

__global__ __launch_bounds__(256) void k_combine(
    const float* __restrict__ y, const int* __restrict__ counts,
    const int* __restrict__ tE, const int* __restrict__ tP,
    const float* __restrict__ tG, float* __restrict__ out) {
  int t = blockIdx.x;
  int c = threadIdx.x;  // H/4 = 256 float4 per token row
  int bases[NE];
  int s = 0;
#pragma unroll
  for (int e = 0; e < NE; e++) { bases[e] = s; s += counts[e]; }
  int e0 = tE[t * 2], e1 = tE[t * 2 + 1];
  int r0 = bases[e0] + tP[t * 2], r1 = bases[e1] + tP[t * 2 + 1];
  float g0 = tG[t * 2], g1 = tG[t * 2 + 1];
  const float4* y4 = (const float4*)y;
  float4* o4 = (float4*)out;
  float4 sv = o4[(size_t)t * (H_DIM / 4) + c];
  float4 a = y4[(size_t)r0 * (H_DIM / 4) + c];
  float4 b = y4[(size_t)r1 * (H_DIM / 4) + c];
  sv.x += g0 * a.x + g1 * b.x;
  sv.y += g0 * a.y + g1 * b.y;
  sv.z += g0 * a.z + g1 * b.z;
  sv.w += g0 * a.w + g1 * b.w;
  o4[(size_t)t * (H_DIM / 4) + c] = sv;
}

extern "C" void kernel_launch(void* const* d_in, const int* in_sizes, int n_in,
                              void* d_out, int out_size, void* d_ws, size_t ws_size,
                              hipStream_t stream) {
  const float* x = (const float*)d_in[0];
  const float* sg_w = (const float*)d_in[1];
  const float* su_w = (const float*)d_in[2];
  const float* sd_w = (const float*)d_in[3];
  const float* router_w = (const float*)d_in[4];
  const float* routing_bias = (const float*)d_in[5];
  const float* wg = (const float*)d_in[6];
  const float* wu = (const float*)d_in[7];
  const float* wd = (const float*)d_in[8];
  float* out = (float*)d_out;
  char* ws = (char*)d_ws;

  __bf16* xb  = (__bf16*)(ws + 0);            //  8,388,608
  __bf16* hs  = (__bf16*)(ws + 8388608);      // 16,777,216
  __bf16* hr  = (__bf16*)(ws + 25165824);     // 33,554,432
  float*  y   = (float*)(ws + 58720256);      // 33,554,432
  int* counts = (int*)(ws + 205520896);
  int* list   = (int*)(ws + 205520960);       // 131,072
  int* tE     = (int*)(ws + 205652032);       // 32,768
  int* tP     = (int*)(ws + 205684800);       // 32,768
  float* tG   = (float*)(ws + 205717568);     // 32,768

  hipMemsetAsync(counts, 0, NE * sizeof(int), stream);
  k_router<<<NT / 4, 256, 0, stream>>>(x, router_w, routing_bias, xb,
                                       counts, list, tE, tP, tG);
  dim3 gu(I_DIM / 64, NT / 128, NE + 1);
  k_upgate97<<<gu, 256, 0, stream>>>(xb, wg, wu, sg_w, su_w, counts, list, hs, hr);
  dim3 gd(H_DIM / 128, NT / 128, NE + 1);
  k_down97<<<gd, 256, 0, stream>>>(hs, hr, wd, sd_w, counts, out, y);
  k_combine<<<NT, 256, 0, stream>>>(y, counts, tE, tP, tG, out);
}

// Round 12
// 372.329 us; speedup vs baseline: 1.3440x; 1.3440x over previous
//
#include <hip/hip_runtime.h>
#include <hip/hip_bf16.h>

#define H_DIM 1024
#define I_DIM 2048
#define NE 8
#define NT 4096

typedef __bf16 bf16x8 __attribute__((ext_vector_type(8)));
typedef __bf16 bf16x4 __attribute__((ext_vector_type(4)));
typedef float f32x4 __attribute__((ext_vector_type(4)));

// 16B-chunk index within a [rows][8-chunk] LDS tile, XOR-swizzled (verified
// conflict-free R1-R11: SQ_LDS_BANK_CONFLICT == 0).
__device__ __forceinline__ int swzc(int r, int j) { return r * 8 + (j ^ (r & 7)); }

// async global->LDS, 16B per lane. LDS dest is wave-uniform base (HW adds lane*16).
__device__ __forceinline__ void gl16(const void* g, void* l) {
  __builtin_amdgcn_global_load_lds(
      (const __attribute__((address_space(1))) unsigned int*)g,
      (__attribute__((address_space(3))) unsigned int*)l, 16, 0, 0);
}

__device__ __forceinline__ bf16x8 cvt8(float4 a, float4 b) {
  bf16x8 r;
  r[0] = (__bf16)a.x; r[1] = (__bf16)a.y; r[2] = (__bf16)a.z; r[3] = (__bf16)a.w;
  r[4] = (__bf16)b.x; r[5] = (__bf16)b.y; r[6] = (__bf16)b.z; r[7] = (__bf16)b.w;
  return r;
}

#define NBW 16384   // wg+wu cast blocks: 2 * 2^21 chunks / 256
#define NBS 2048    // sg+su cast blocks: 2 * 2^18 chunks / 256

// Prep: cast ONLY upgate's weights (wg,wu,sg,su) + router. wd/sd cast is
// deferred into the upgate launch (runs concurrent with GEMM; down consumes
// it only in the next launch).
__global__ __launch_bounds__(256) void k_prep(
    const float* __restrict__ wg, const float* __restrict__ wu,
    const float* __restrict__ sg, const float* __restrict__ su,
    __bf16* __restrict__ wgb, __bf16* __restrict__ wub,
    __bf16* __restrict__ sgb, __bf16* __restrict__ sub,
    const float* __restrict__ x, const float* __restrict__ rw,
    const float* __restrict__ rbias, __bf16* __restrict__ xb,
    int* __restrict__ counts, int* __restrict__ list,
    int* __restrict__ tE, int* __restrict__ tP, float* __restrict__ tG) {
  if (blockIdx.x < NBW + NBS) {
    const float* s; __bf16* d; int off;
    if (blockIdx.x < NBW) {
      int i = blockIdx.x * 256 + threadIdx.x;
      if (i < (1 << 21)) { s = wg; d = wgb; off = i; }
      else { s = wu; d = wub; off = i - (1 << 21); }
    } else {
      int i = (blockIdx.x - NBW) * 256 + threadIdx.x;
      if (i < (1 << 18)) { s = sg; d = sgb; off = i; }
      else { s = su; d = sub; off = i - (1 << 18); }
    }
    const float4* s4 = (const float4*)s;
    float4 a = s4[(size_t)off * 2], b = s4[(size_t)off * 2 + 1];
    ((bf16x8*)d)[off] = cvt8(a, b);
    return;
  }
  // ---- router (sigmoid top-2 renorm + lists; fuses x->bf16) ----
  int blk = blockIdx.x - (NBW + NBS);         // 0..1023
  int wv = threadIdx.x >> 6, lane = threadIdx.x & 63;
  int t = blk * 4 + wv;
  float acc[NE];
#pragma unroll
  for (int e = 0; e < NE; e++) acc[e] = 0.f;
  const float4* xr = (const float4*)(x + (size_t)t * H_DIM);
  const float4* wr4 = (const float4*)rw;
  bf16x4* xo = (bf16x4*)xb + (size_t)t * (H_DIM / 4);
#pragma unroll
  for (int it = 0; it < 4; ++it) {
    int c = it * 64 + lane;
    float4 xv = xr[c];
    bf16x4 bv;
    bv[0] = (__bf16)xv.x; bv[1] = (__bf16)xv.y;
    bv[2] = (__bf16)xv.z; bv[3] = (__bf16)xv.w;
    xo[c] = bv;
#pragma unroll
    for (int e = 0; e < NE; e++) {
      float4 wv2 = wr4[e * (H_DIM / 4) + c];
      acc[e] += xv.x * wv2.x + xv.y * wv2.y + xv.z * wv2.z + xv.w * wv2.w;
    }
  }
#pragma unroll
  for (int e = 0; e < NE; e++) {
#pragma unroll
    for (int off = 32; off > 0; off >>= 1) acc[e] += __shfl_xor(acc[e], off, 64);
  }
  if (lane == 0) {
    float p[NE];
#pragma unroll
    for (int e = 0; e < NE; e++) p[e] = 1.f / (1.f + expf(-(acc[e] + rbias[e])));
    int e0 = 0;
#pragma unroll
    for (int e = 1; e < NE; e++) if (p[e] > p[e0]) e0 = e;
    int e1 = -1;
#pragma unroll
    for (int e = 0; e < NE; e++) if (e != e0 && (e1 < 0 || p[e] > p[e1])) e1 = e;
    float s = p[e0] + p[e1];
    float g0 = p[e0] / s, g1 = p[e1] / s;
    int p0 = atomicAdd(&counts[e0], 1);
    int p1 = atomicAdd(&counts[e1], 1);
    list[e0 * NT + p0] = t;
    list[e1 * NT + p1] = t;
    tE[t * 2] = e0; tE[t * 2 + 1] = e1;
    tP[t * 2] = p0; tP[t * 2 + 1] = p1;
    tG[t * 2] = g0; tG[t * 2 + 1] = g1;
  }
}

// ---------------------------------------------------------------------------
// Fused gate+up GEMM (R9/R10 verified m97 config: 128 rows x 64 i-cols x
// {g,u}, BK=64, 4 waves, 64 KB dbuf LDS -> 2 blocks/CU, bf16 precast
// weights via global_load_lds). Grid z extended to 18: z<9 = GEMM slices,
// z>=9 = wd/sd fp32->bf16 cast blocks riding in upgate's HBM headroom
// (down, which consumes wdb/sdb, launches strictly after this kernel).
// ---------------------------------------------------------------------------
__global__ __launch_bounds__(256, 2) void k_upgate97(
    const __bf16* __restrict__ xb, const __bf16* __restrict__ wgb,
    const __bf16* __restrict__ wub, const __bf16* __restrict__ sgb,
    const __bf16* __restrict__ sub, const int* __restrict__ counts,
    const int* __restrict__ list,
    __bf16* __restrict__ hs, __bf16* __restrict__ hr,
    const float* __restrict__ wd, const float* __restrict__ sdw,
    __bf16* __restrict__ wdb, __bf16* __restrict__ sdb) {
  int z = blockIdx.z;
  if (z >= NE + 1) {
    // ---- wd/sd cast: (z-9) in [0,9) -> 9216 blocks, 1 chunk/thread ----
    int id = (((z - (NE + 1)) * 32 + blockIdx.y) * 32 + blockIdx.x) * 256 + threadIdx.x;
    const float* s; __bf16* d; int off;
    if (id < (1 << 21)) { s = wd; d = wdb; off = id; }
    else { s = sdw; d = sdb; off = id - (1 << 21); }
    const float4* s4 = (const float4*)s;
    float4 a = s4[(size_t)off * 2], b = s4[(size_t)off * 2 + 1];
    ((bf16x8*)d)[off] = cvt8(a, b);
    return;
  }
  int m0 = blockIdx.y * 128, n0 = blockIdx.x * 64;
  bool sh = (z == NE);
  int count, base = 0;
  const __bf16 *Bg, *Bu;
  if (sh) {
    count = NT; Bg = sgb; Bu = sub;
  } else {
    count = counts[z];
    if (m0 >= count) return;
    for (int e = 0; e < z; e++) base += counts[e];
    Bg = wgb + (size_t)z * (I_DIM * H_DIM);
    Bu = wub + (size_t)z * (I_DIM * H_DIM);
  }

  __shared__ bf16x8 lds[4096];   // [2][A 1024 | B 1024] = 64 KB

  int tid = threadIdx.x, lane = tid & 63, w = tid >> 6;
  int wr = w >> 1, wc = w & 1;
  int fr = lane & 15, fs = lane >> 4;

  const bf16x8* a8 = (const bf16x8*)xb;
  const bf16x8* g8 = (const bf16x8*)Bg;
  const bf16x8* u8 = (const bf16x8*)Bu;

  const bf16x8* pA[4];
  const bf16x8* pB[4];
#pragma unroll
  for (int q = 0; q < 4; q++) {
    int c = q * 256 + tid;                  // chunk 0..1023 (128 rows x 8)
    int r = c >> 3, j = (c & 7) ^ (r & 7);
    int gr = m0 + r;
    int tok = sh ? gr : ((gr < count) ? list[z * NT + gr] : list[z * NT]);
    pA[q] = a8 + (size_t)tok * (H_DIM / 8) + j;
    int G = r >> 6, gu = (r >> 5) & 1, cc = r & 31;
    pB[q] = (gu ? u8 : g8) + (size_t)(n0 + G * 32 + cc) * (H_DIM / 8) + j;
  }

  f32x4 acc[4][4];
#pragma unroll
  for (int m = 0; m < 4; m++)
#pragma unroll
    for (int n = 0; n < 4; n++) acc[m][n] = (f32x4){0.f, 0.f, 0.f, 0.f};

  // prologue: stage tile 0 into buf 0
  {
    bf16x8* dA = lds;
    bf16x8* dB = lds + 1024;
#pragma unroll
    for (int q = 0; q < 4; q++) {
      gl16(pA[q], dA + q * 256 + w * 64);
      gl16(pB[q], dB + q * 256 + w * 64);
    }
  }

  const int NK = H_DIM / 64;  // 16
  for (int kt = 0; kt < NK; ++kt) {
    __syncthreads();           // drains tile kt's loads; WAR-fences buf^1
    if (kt + 1 < NK) {
      bf16x8* dA = lds + ((kt + 1) & 1) * 2048;
      bf16x8* dB = dA + 1024;
      int ko = (kt + 1) * 8;
#pragma unroll
      for (int q = 0; q < 4; q++) {
        gl16(pA[q] + ko, dA + q * 256 + w * 64);
        gl16(pB[q] + ko, dB + q * 256 + w * 64);
      }
    }
    const bf16x8* Ac = lds + (kt & 1) * 2048;
    const bf16x8* Bc = Ac + 1024;
#pragma unroll
    for (int ks = 0; ks < 2; ks++) {
      bf16x8 af[4], bfr[4];
#pragma unroll
      for (int mf = 0; mf < 4; mf++) af[mf] = Ac[swzc(wr * 64 + mf * 16 + fr, ks * 4 + fs)];
#pragma unroll
      for (int nf = 0; nf < 4; nf++) bfr[nf] = Bc[swzc(wc * 64 + nf * 16 + fr, ks * 4 + fs)];
      __builtin_amdgcn_s_setprio(1);
#pragma unroll
      for (int m = 0; m < 4; m++)
#pragma unroll
        for (int n = 0; n < 4; n++)
          acc[m][n] = __builtin_amdgcn_mfma_f32_16x16x32_bf16(af[m], bfr[n], acc[m][n], 0, 0, 0);
      __builtin_amdgcn_s_setprio(0);
    }
  }

  // epilogue: h = silu(g)*u; g = acc[m][np], u = acc[m][np+2]
#pragma unroll
  for (int m = 0; m < 4; m++)
#pragma unroll
    for (int np = 0; np < 2; np++)
#pragma unroll
      for (int q2 = 0; q2 < 4; q2++) {
        int row = wr * 64 + m * 16 + fs * 4 + q2;
        int col = n0 + wc * 32 + np * 16 + fr;
        float g = acc[m][np][q2], u = acc[m][np + 2][q2];
        float h = g * u / (1.f + expf(-g));
        __bf16 hb = (__bf16)h;
        int grow = m0 + row;
        if (sh) hs[(size_t)grow * I_DIM + col] = hb;
        else if (grow < count) hr[(size_t)(base + grow) * I_DIM + col] = hb;
      }
}

// ---------------------------------------------------------------------------
// Down GEMM (R9/R10 verified): 128x128 tile, BK=64, 4 waves, 64 KB dbuf LDS
// -> 2 blocks/CU. bf16 weights (cast completed inside the upgate launch).
// ---------------------------------------------------------------------------
__global__ __launch_bounds__(256, 2) void k_down97(
    const __bf16* __restrict__ hs, const __bf16* __restrict__ hr,
    const __bf16* __restrict__ wdb, const __bf16* __restrict__ sdb,
    const int* __restrict__ counts,
    float* __restrict__ out, float* __restrict__ y) {
  int z = blockIdx.z;
  int m0 = blockIdx.y * 128, n0 = blockIdx.x * 128;
  bool sh = (z == NE);
  int count, base = 0;
  const __bf16 *B, *A;
  if (sh) {
    count = NT; B = sdb; A = hs;
  } else {
    count = counts[z];
    if (m0 >= count) return;
    for (int e = 0; e < z; e++) base += counts[e];
    B = wdb + (size_t)z * (H_DIM * I_DIM);
    A = hr + (size_t)base * I_DIM;
  }

  __shared__ bf16x8 lds[4096];   // [2][A 1024 | B 1024] = 64 KB

  int tid = threadIdx.x, lane = tid & 63, w = tid >> 6;
  int wr = w >> 1, wc = w & 1;
  int fr = lane & 15, fs = lane >> 4;

  const bf16x8* a8 = (const bf16x8*)A;
  const bf16x8* b8 = (const bf16x8*)B;

  const bf16x8* pA[4];
  const bf16x8* pB[4];
#pragma unroll
  for (int q = 0; q < 4; q++) {
    int c = q * 256 + tid;                  // chunk 0..1023 (128 rows x 8)
    int r = c >> 3, j = (c & 7) ^ (r & 7);
    int ra = m0 + r; if (ra >= count) ra = count - 1;
    pA[q] = a8 + (size_t)ra * (I_DIM / 8) + j;
    pB[q] = b8 + (size_t)(n0 + r) * (I_DIM / 8) + j;
  }

  f32x4 acc[4][4];
#pragma unroll
  for (int m = 0; m < 4; m++)
#pragma unroll
    for (int n = 0; n < 4; n++) acc[m][n] = (f32x4){0.f, 0.f, 0.f, 0.f};

  // prologue: stage tile 0 into buf 0
  {
    bf16x8* dA = lds;
    bf16x8* dB = lds + 1024;
#pragma unroll
    for (int q = 0; q < 4; q++) {
      gl16(pA[q], dA + q * 256 + w * 64);
      gl16(pB[q], dB + q * 256 + w * 64);
    }
  }

  const int NK = I_DIM / 64;  // 32
  for (int kt = 0; kt < NK; ++kt) {
    __syncthreads();           // drains tile kt's loads; WAR-fences buf^1
    if (kt + 1 < NK) {
      bf16x8* dA = lds + ((kt + 1) & 1) * 2048;
      bf16x8* dB = dA + 1024;
      int ko = (kt + 1) * 8;
#pragma unroll
      for (int q = 0; q < 4; q++) {
        gl16(pA[q] + ko, dA + q * 256 + w * 64);
        gl16(pB[q] + ko, dB + q * 256 + w * 64);
      }
    }
    const bf16x8* Ac = lds + (kt & 1) * 2048;
    const bf16x8* Bc = Ac + 1024;
#pragma unroll
    for (int ks = 0; ks < 2; ks++) {
      bf16x8 af[4], bfr[4];
#pragma unroll
      for (int mf = 0; mf < 4; mf++) af[mf] = Ac[swzc(wr * 64 + mf * 16 + fr, ks * 4 + fs)];
#pragma unroll
      for (int nf = 0; nf < 4; nf++) bfr[nf] = Bc[swzc(wc * 64 + nf * 16 + fr, ks * 4 + fs)];
      __builtin_amdgcn_s_setprio(1);
#pragma unroll
      for (int m = 0; m < 4; m++)
#pragma unroll
        for (int n = 0; n < 4; n++)
          acc[m][n] = __builtin_amdgcn_mfma_f32_16x16x32_bf16(af[m], bfr[n], acc[m][n], 0, 0, 0);
      __builtin_amdgcn_s_setprio(0);
    }
  }

#pragma unroll
  for (int m = 0; m < 4; m++)
#pragma unroll
    for (int n = 0; n < 4; n++)
#pragma unroll
      for (int q2 = 0; q2 < 4; q2++) {
        int row = wr * 64 + m * 16 + fs * 4 + q2;
        int col = n0 + wc * 64 + n * 16 + fr;
        float v = acc[m][n][q2];
        int grow = m0 + row;
        if (sh) out[(size_t)grow * H_DIM + col] = v;
        else if (grow < count) y[(size_t)(base + grow) * H_DIM + col] = v;
      }
}

__global__ __launch_bounds__(256) void k_combine(
    const float* __restrict__ y, const int* __restrict__ counts,
    const int* __restrict__ tE, const int* __restrict__ tP,
    const float* __restrict__ tG, float* __restrict__ out) {
  int t = blockIdx.x;
  int c = threadIdx.x;  // H/4 = 256 float4 per token row
  int bases[NE];
  int s = 0;
#pragma unroll
  for (int e = 0; e < NE; e++) { bases[e] = s; s += counts[e]; }
  int e0 = tE[t * 2], e1 = tE[t * 2 + 1];
  int r0 = bases[e0] + tP[t * 2], r1 = bases[e1] + tP[t * 2 + 1];
  float g0 = tG[t * 2], g1 = tG[t * 2 + 1];
  const float4* y4 = (const float4*)y;
  float4* o4 = (float4*)out;
  float4 sv = o4[(size_t)t * (H_DIM / 4) + c];
  float4 a = y4[(size_t)r0 * (H_DIM / 4) + c];
  float4 b = y4[(size_t)r1 * (H_DIM / 4) + c];
  sv.x += g0 * a.x + g1 * b.x;
  sv.y += g0 * a.y + g1 * b.y;
  sv.z += g0 * a.z + g1 * b.z;
  sv.w += g0 * a.w + g1 * b.w;
  o4[(size_t)t * (H_DIM / 4) + c] = sv;
}

extern "C" void kernel_launch(void* const* d_in, const int* in_sizes, int n_in,
                              void* d_out, int out_size, void* d_ws, size_t ws_size,
                              hipStream_t stream) {
  const float* x = (const float*)d_in[0];
  const float* sg_w = (const float*)d_in[1];
  const float* su_w = (const float*)d_in[2];
  const float* sd_w = (const float*)d_in[3];
  const float* router_w = (const float*)d_in[4];
  const float* routing_bias = (const float*)d_in[5];
  const float* wg = (const float*)d_in[6];
  const float* wu = (const float*)d_in[7];
  const float* wd = (const float*)d_in[8];
  float* out = (float*)d_out;
  char* ws = (char*)d_ws;

  __bf16* xb  = (__bf16*)(ws + 0);            //  8,388,608
  __bf16* hs  = (__bf16*)(ws + 8388608);      // 16,777,216
  __bf16* hr  = (__bf16*)(ws + 25165824);     // 33,554,432
  float*  y   = (float*)(ws + 58720256);      // 33,554,432
  __bf16* wgb = (__bf16*)(ws + 92274688);     // 33,554,432
  __bf16* wub = (__bf16*)(ws + 125829120);    // 33,554,432
  __bf16* wdb = (__bf16*)(ws + 159383552);    // 33,554,432
  __bf16* sgb = (__bf16*)(ws + 192937984);    //  4,194,304
  __bf16* sub = (__bf16*)(ws + 197132288);    //  4,194,304
  __bf16* sdb = (__bf16*)(ws + 201326592);    //  4,194,304
  int* counts = (int*)(ws + 205520896);
  int* list   = (int*)(ws + 205520960);       // 131,072
  int* tE     = (int*)(ws + 205652032);       // 32,768
  int* tP     = (int*)(ws + 205684800);       // 32,768
  float* tG   = (float*)(ws + 205717568);     // 32,768

  hipMemsetAsync(counts, 0, NE * sizeof(int), stream);
  // prep: wg/wu/sg/su cast + router (what upgate needs)
  k_prep<<<NBW + NBS + NT / 4, 256, 0, stream>>>(
      wg, wu, sg_w, su_w, wgb, wub, sgb, sub,
      x, router_w, routing_bias, xb, counts, list, tE, tP, tG);
  // upgate GEMM (z<9) + wd/sd cast riding along (z in [9,18))
  dim3 gu(I_DIM / 64, NT / 128, (NE + 1) + 9);
  k_upgate97<<<gu, 256, 0, stream>>>(xb, wgb, wub, sgb, sub, counts, list,
                                     hs, hr, wd, sd_w, wdb, sdb);
  dim3 gd(H_DIM / 128, NT / 128, NE + 1);
  k_down97<<<gd, 256, 0, stream>>>(hs, hr, wdb, sdb, counts, out, y);
  k_combine<<<NT, 256, 0, stream>>>(y, counts, tE, tP, tG, out);
}

// Round 13
// 283.629 us; speedup vs baseline: 1.7644x; 1.3127x over previous
//
#include <hip/hip_runtime.h>
#include <hip/hip_bf16.h>

#define H_DIM 1024
#define I_DIM 2048
#define NE 8
#define NT 4096

typedef __bf16 bf16x8 __attribute__((ext_vector_type(8)));
typedef __bf16 bf16x4 __attribute__((ext_vector_type(4)));
typedef float f32x4 __attribute__((ext_vector_type(4)));

// 16B-chunk index within a [rows][8-chunk] LDS tile, XOR-swizzled (verified
// conflict-free R1-R12: SQ_LDS_BANK_CONFLICT == 0).
__device__ __forceinline__ int swzc(int r, int j) { return r * 8 + (j ^ (r & 7)); }

// async global->LDS, 16B per lane. LDS dest is wave-uniform base (HW adds lane*16).
__device__ __forceinline__ void gl16(const void* g, void* l) {
  __builtin_amdgcn_global_load_lds(
      (const __attribute__((address_space(1))) unsigned int*)g,
      (__attribute__((address_space(3))) unsigned int*)l, 16, 0, 0);
}

__device__ __forceinline__ bf16x8 cvt8(float4 a, float4 b) {
  bf16x8 r;
  r[0] = (__bf16)a.x; r[1] = (__bf16)a.y; r[2] = (__bf16)a.z; r[3] = (__bf16)a.w;
  r[4] = (__bf16)b.x; r[5] = (__bf16)b.y; r[6] = (__bf16)b.z; r[7] = (__bf16)b.w;
  return r;
}

#define NBW 16384   // wg+wu cast blocks: 2 * 2^21 chunks / 256
#define NBS 2048    // sg+su cast blocks: 2 * 2^18 chunks / 256

// Prep: cast upgate's weights (wg,wu,sg,su) + router SCORING ONLY (no
// atomics — the 8-counter atomicAdd chain was ~120 us of serialized L2 RMWs;
// slot assignment moved to k_sched's LDS histogram).
__global__ __launch_bounds__(256) void k_prep(
    const float* __restrict__ wg, const float* __restrict__ wu,
    const float* __restrict__ sg, const float* __restrict__ su,
    __bf16* __restrict__ wgb, __bf16* __restrict__ wub,
    __bf16* __restrict__ sgb, __bf16* __restrict__ sub,
    const float* __restrict__ x, const float* __restrict__ rw,
    const float* __restrict__ rbias, __bf16* __restrict__ xb,
    int* __restrict__ tE, float* __restrict__ tG) {
  if (blockIdx.x < NBW + NBS) {
    const float* s; __bf16* d; int off;
    if (blockIdx.x < NBW) {
      int i = blockIdx.x * 256 + threadIdx.x;
      if (i < (1 << 21)) { s = wg; d = wgb; off = i; }
      else { s = wu; d = wub; off = i - (1 << 21); }
    } else {
      int i = (blockIdx.x - NBW) * 256 + threadIdx.x;
      if (i < (1 << 18)) { s = sg; d = sgb; off = i; }
      else { s = su; d = sub; off = i - (1 << 18); }
    }
    const float4* s4 = (const float4*)s;
    float4 a = s4[(size_t)off * 2], b = s4[(size_t)off * 2 + 1];
    ((bf16x8*)d)[off] = cvt8(a, b);
    return;
  }
  // ---- router scoring (sigmoid top-2 renorm; fuses x->bf16; NO atomics) ----
  int blk = blockIdx.x - (NBW + NBS);         // 0..1023
  int wv = threadIdx.x >> 6, lane = threadIdx.x & 63;
  int t = blk * 4 + wv;
  float acc[NE];
#pragma unroll
  for (int e = 0; e < NE; e++) acc[e] = 0.f;
  const float4* xr = (const float4*)(x + (size_t)t * H_DIM);
  const float4* wr4 = (const float4*)rw;
  bf16x4* xo = (bf16x4*)xb + (size_t)t * (H_DIM / 4);
#pragma unroll
  for (int it = 0; it < 4; ++it) {
    int c = it * 64 + lane;
    float4 xv = xr[c];
    bf16x4 bv;
    bv[0] = (__bf16)xv.x; bv[1] = (__bf16)xv.y;
    bv[2] = (__bf16)xv.z; bv[3] = (__bf16)xv.w;
    xo[c] = bv;
#pragma unroll
    for (int e = 0; e < NE; e++) {
      float4 wv2 = wr4[e * (H_DIM / 4) + c];
      acc[e] += xv.x * wv2.x + xv.y * wv2.y + xv.z * wv2.z + xv.w * wv2.w;
    }
  }
#pragma unroll
  for (int e = 0; e < NE; e++) {
#pragma unroll
    for (int off = 32; off > 0; off >>= 1) acc[e] += __shfl_xor(acc[e], off, 64);
  }
  if (lane == 0) {
    float p[NE];
#pragma unroll
    for (int e = 0; e < NE; e++) p[e] = 1.f / (1.f + expf(-(acc[e] + rbias[e])));
    int e0 = 0;
#pragma unroll
    for (int e = 1; e < NE; e++) if (p[e] > p[e0]) e0 = e;
    int e1 = -1;
#pragma unroll
    for (int e = 0; e < NE; e++) if (e != e0 && (e1 < 0 || p[e] > p[e1])) e1 = e;
    float s = p[e0] + p[e1];
    tE[t * 2] = e0; tE[t * 2 + 1] = e1;
    tG[t * 2] = p[e0] / s; tG[t * 2 + 1] = p[e1] / s;
  }
}

// Slot assignment: LDS histogram over tE -> counts, list, tP. One block;
// 8192 LDS atomics on 8 words (~us) replaces 8192 serialized L2 RMWs.
__global__ __launch_bounds__(1024) void k_sched(
    const int* __restrict__ tE, int* __restrict__ counts,
    int* __restrict__ list, int* __restrict__ tP) {
  __shared__ int lc[NE];
  int tid = threadIdx.x;
  if (tid < NE) lc[tid] = 0;
  __syncthreads();
  for (int t = tid; t < NT; t += 1024) {
    int e0 = tE[t * 2], e1 = tE[t * 2 + 1];
    int p0 = atomicAdd(&lc[e0], 1);
    list[e0 * NT + p0] = t;
    tP[t * 2] = p0;
    int p1 = atomicAdd(&lc[e1], 1);
    list[e1 * NT + p1] = t;
    tP[t * 2 + 1] = p1;
  }
  __syncthreads();
  if (tid < NE) counts[tid] = lc[tid];
}

// ---------------------------------------------------------------------------
// Fused gate+up GEMM (verified m97 config: 128 rows x 64 i-cols x {g,u},
// BK=64, 4 waves, 64 KB dbuf LDS -> 2 blocks/CU, bf16 precast weights via
// global_load_lds). Grid z: z<9 GEMM, z>=9 wd/sd cast riding along (down
// consumes wdb/sdb only in the next launch).
// ---------------------------------------------------------------------------
__global__ __launch_bounds__(256, 2) void k_upgate97(
    const __bf16* __restrict__ xb, const __bf16* __restrict__ wgb,
    const __bf16* __restrict__ wub, const __bf16* __restrict__ sgb,
    const __bf16* __restrict__ sub, const int* __restrict__ counts,
    const int* __restrict__ list,
    __bf16* __restrict__ hs, __bf16* __restrict__ hr,
    const float* __restrict__ wd, const float* __restrict__ sdw,
    __bf16* __restrict__ wdb, __bf16* __restrict__ sdb) {
  int z = blockIdx.z;
  if (z >= NE + 1) {
    // ---- wd/sd cast: (z-9) in [0,9) -> 9216 blocks, 1 chunk/thread ----
    int id = (((z - (NE + 1)) * 32 + blockIdx.y) * 32 + blockIdx.x) * 256 + threadIdx.x;
    const float* s; __bf16* d; int off;
    if (id < (1 << 21)) { s = wd; d = wdb; off = id; }
    else { s = sdw; d = sdb; off = id - (1 << 21); }
    const float4* s4 = (const float4*)s;
    float4 a = s4[(size_t)off * 2], b = s4[(size_t)off * 2 + 1];
    ((bf16x8*)d)[off] = cvt8(a, b);
    return;
  }
  int m0 = blockIdx.y * 128, n0 = blockIdx.x * 64;
  bool sh = (z == NE);
  int count, base = 0;
  const __bf16 *Bg, *Bu;
  if (sh) {
    count = NT; Bg = sgb; Bu = sub;
  } else {
    count = counts[z];
    if (m0 >= count) return;
    for (int e = 0; e < z; e++) base += counts[e];
    Bg = wgb + (size_t)z * (I_DIM * H_DIM);
    Bu = wub + (size_t)z * (I_DIM * H_DIM);
  }

  __shared__ bf16x8 lds[4096];   // [2][A 1024 | B 1024] = 64 KB

  int tid = threadIdx.x, lane = tid & 63, w = tid >> 6;
  int wr = w >> 1, wc = w & 1;
  int fr = lane & 15, fs = lane >> 4;

  const bf16x8* a8 = (const bf16x8*)xb;
  const bf16x8* g8 = (const bf16x8*)Bg;
  const bf16x8* u8 = (const bf16x8*)Bu;

  const bf16x8* pA[4];
  const bf16x8* pB[4];
#pragma unroll
  for (int q = 0; q < 4; q++) {
    int c = q * 256 + tid;                  // chunk 0..1023 (128 rows x 8)
    int r = c >> 3, j = (c & 7) ^ (r & 7);
    int gr = m0 + r;
    int tok = sh ? gr : ((gr < count) ? list[z * NT + gr] : list[z * NT]);
    pA[q] = a8 + (size_t)tok * (H_DIM / 8) + j;
    int G = r >> 6, gu = (r >> 5) & 1, cc = r & 31;
    pB[q] = (gu ? u8 : g8) + (size_t)(n0 + G * 32 + cc) * (H_DIM / 8) + j;
  }

  f32x4 acc[4][4];
#pragma unroll
  for (int m = 0; m < 4; m++)
#pragma unroll
    for (int n = 0; n < 4; n++) acc[m][n] = (f32x4){0.f, 0.f, 0.f, 0.f};

  // prologue: stage tile 0 into buf 0
  {
    bf16x8* dA = lds;
    bf16x8* dB = lds + 1024;
#pragma unroll
    for (int q = 0; q < 4; q++) {
      gl16(pA[q], dA + q * 256 + w * 64);
      gl16(pB[q], dB + q * 256 + w * 64);
    }
  }

  const int NK = H_DIM / 64;  // 16
  for (int kt = 0; kt < NK; ++kt) {
    __syncthreads();           // drains tile kt's loads; WAR-fences buf^1
    if (kt + 1 < NK) {
      bf16x8* dA = lds + ((kt + 1) & 1) * 2048;
      bf16x8* dB = dA + 1024;
      int ko = (kt + 1) * 8;
#pragma unroll
      for (int q = 0; q < 4; q++) {
        gl16(pA[q] + ko, dA + q * 256 + w * 64);
        gl16(pB[q] + ko, dB + q * 256 + w * 64);
      }
    }
    const bf16x8* Ac = lds + (kt & 1) * 2048;
    const bf16x8* Bc = Ac + 1024;
#pragma unroll
    for (int ks = 0; ks < 2; ks++) {
      bf16x8 af[4], bfr[4];
#pragma unroll
      for (int mf = 0; mf < 4; mf++) af[mf] = Ac[swzc(wr * 64 + mf * 16 + fr, ks * 4 + fs)];
#pragma unroll
      for (int nf = 0; nf < 4; nf++) bfr[nf] = Bc[swzc(wc * 64 + nf * 16 + fr, ks * 4 + fs)];
      __builtin_amdgcn_s_setprio(1);
#pragma unroll
      for (int m = 0; m < 4; m++)
#pragma unroll
        for (int n = 0; n < 4; n++)
          acc[m][n] = __builtin_amdgcn_mfma_f32_16x16x32_bf16(af[m], bfr[n], acc[m][n], 0, 0, 0);
      __builtin_amdgcn_s_setprio(0);
    }
  }

  // epilogue: h = silu(g)*u; g = acc[m][np], u = acc[m][np+2]
#pragma unroll
  for (int m = 0; m < 4; m++)
#pragma unroll
    for (int np = 0; np < 2; np++)
#pragma unroll
      for (int q2 = 0; q2 < 4; q2++) {
        int row = wr * 64 + m * 16 + fs * 4 + q2;
        int col = n0 + wc * 32 + np * 16 + fr;
        float g = acc[m][np][q2], u = acc[m][np + 2][q2];
        float h = g * u / (1.f + expf(-g));
        __bf16 hb = (__bf16)h;
        int grow = m0 + row;
        if (sh) hs[(size_t)grow * I_DIM + col] = hb;
        else if (grow < count) hr[(size_t)(base + grow) * I_DIM + col] = hb;
      }
}

// ---------------------------------------------------------------------------
// Down GEMM (verified): 128x128 tile, BK=64, 4 waves, 64 KB dbuf LDS ->
// 2 blocks/CU. bf16 weights (cast completed inside the upgate launch).
// ---------------------------------------------------------------------------
__global__ __launch_bounds__(256, 2) void k_down97(
    const __bf16* __restrict__ hs, const __bf16* __restrict__ hr,
    const __bf16* __restrict__ wdb, const __bf16* __restrict__ sdb,
    const int* __restrict__ counts,
    float* __restrict__ out, float* __restrict__ y) {
  int z = blockIdx.z;
  int m0 = blockIdx.y * 128, n0 = blockIdx.x * 128;
  bool sh = (z == NE);
  int count, base = 0;
  const __bf16 *B, *A;
  if (sh) {
    count = NT; B = sdb; A = hs;
  } else {
    count = counts[z];
    if (m0 >= count) return;
    for (int e = 0; e < z; e++) base += counts[e];
    B = wdb + (size_t)z * (H_DIM * I_DIM);
    A = hr + (size_t)base * I_DIM;
  }

  __shared__ bf16x8 lds[4096];   // [2][A 1024 | B 1024] = 64 KB

  int tid = threadIdx.x, lane = tid & 63, w = tid >> 6;
  int wr = w >> 1, wc = w & 1;
  int fr = lane & 15, fs = lane >> 4;

  const bf16x8* a8 = (const bf16x8*)A;
  const bf16x8* b8 = (const bf16x8*)B;

  const bf16x8* pA[4];
  const bf16x8* pB[4];
#pragma unroll
  for (int q = 0; q < 4; q++) {
    int c = q * 256 + tid;                  // chunk 0..1023 (128 rows x 8)
    int r = c >> 3, j = (c & 7) ^ (r & 7);
    int ra = m0 + r; if (ra >= count) ra = count - 1;
    pA[q] = a8 + (size_t)ra * (I_DIM / 8) + j;
    pB[q] = b8 + (size_t)(n0 + r) * (I_DIM / 8) + j;
  }

  f32x4 acc[4][4];
#pragma unroll
  for (int m = 0; m < 4; m++)
#pragma unroll
    for (int n = 0; n < 4; n++) acc[m][n] = (f32x4){0.f, 0.f, 0.f, 0.f};

  // prologue: stage tile 0 into buf 0
  {
    bf16x8* dA = lds;
    bf16x8* dB = lds + 1024;
#pragma unroll
    for (int q = 0; q < 4; q++) {
      gl16(pA[q], dA + q * 256 + w * 64);
      gl16(pB[q], dB + q * 256 + w * 64);
    }
  }

  const int NK = I_DIM / 64;  // 32
  for (int kt = 0; kt < NK; ++kt) {
    __syncthreads();           // drains tile kt's loads; WAR-fences buf^1
    if (kt + 1 < NK) {
      bf16x8* dA = lds + ((kt + 1) & 1) * 2048;
      bf16x8* dB = dA + 1024;
      int ko = (kt + 1) * 8;
#pragma unroll
      for (int q = 0; q < 4; q++) {
        gl16(pA[q] + ko, dA + q * 256 + w * 64);
        gl16(pB[q] + ko, dB + q * 256 + w * 64);
      }
    }
    const bf16x8* Ac = lds + (kt & 1) * 2048;
    const bf16x8* Bc = Ac + 1024;
#pragma unroll
    for (int ks = 0; ks < 2; ks++) {
      bf16x8 af[4], bfr[4];
#pragma unroll
      for (int mf = 0; mf < 4; mf++) af[mf] = Ac[swzc(wr * 64 + mf * 16 + fr, ks * 4 + fs)];
#pragma unroll
      for (int nf = 0; nf < 4; nf++) bfr[nf] = Bc[swzc(wc * 64 + nf * 16 + fr, ks * 4 + fs)];
      __builtin_amdgcn_s_setprio(1);
#pragma unroll
      for (int m = 0; m < 4; m++)
#pragma unroll
        for (int n = 0; n < 4; n++)
          acc[m][n] = __builtin_amdgcn_mfma_f32_16x16x32_bf16(af[m], bfr[n], acc[m][n], 0, 0, 0);
      __builtin_amdgcn_s_setprio(0);
    }
  }

#pragma unroll
  for (int m = 0; m < 4; m++)
#pragma unroll
    for (int n = 0; n < 4; n++)
#pragma unroll
      for (int q2 = 0; q2 < 4; q2++) {
        int row = wr * 64 + m * 16 + fs * 4 + q2;
        int col = n0 + wc * 64 + n * 16 + fr;
        float v = acc[m][n][q2];
        int grow = m0 + row;
        if (sh) out[(size_t)grow * H_DIM + col] = v;
        else if (grow < count) y[(size_t)(base + grow) * H_DIM + col] = v;
      }
}

__global__ __launch_bounds__(256) void k_combine(
    const float* __restrict__ y, const int* __restrict__ counts,
    const int* __restrict__ tE, const int* __restrict__ tP,
    const float* __restrict__ tG, float* __restrict__ out) {
  int t = blockIdx.x;
  int c = threadIdx.x;  // H/4 = 256 float4 per token row
  int bases[NE];
  int s = 0;
#pragma unroll
  for (int e = 0; e < NE; e++) { bases[e] = s; s += counts[e]; }
  int e0 = tE[t * 2], e1 = tE[t * 2 + 1];
  int r0 = bases[e0] + tP[t * 2], r1 = bases[e1] + tP[t * 2 + 1];
  float g0 = tG[t * 2], g1 = tG[t * 2 + 1];
  const float4* y4 = (const float4*)y;
  float4* o4 = (float4*)out;
  float4 sv = o4[(size_t)t * (H_DIM / 4) + c];
  float4 a = y4[(size_t)r0 * (H_DIM / 4) + c];
  float4 b = y4[(size_t)r1 * (H_DIM / 4) + c];
  sv.x += g0 * a.x + g1 * b.x;
  sv.y += g0 * a.y + g1 * b.y;
  sv.z += g0 * a.z + g1 * b.z;
  sv.w += g0 * a.w + g1 * b.w;
  o4[(size_t)t * (H_DIM / 4) + c] = sv;
}

extern "C" void kernel_launch(void* const* d_in, const int* in_sizes, int n_in,
                              void* d_out, int out_size, void* d_ws, size_t ws_size,
                              hipStream_t stream) {
  const float* x = (const float*)d_in[0];
  const float* sg_w = (const float*)d_in[1];
  const float* su_w = (const float*)d_in[2];
  const float* sd_w = (const float*)d_in[3];
  const float* router_w = (const float*)d_in[4];
  const float* routing_bias = (const float*)d_in[5];
  const float* wg = (const float*)d_in[6];
  const float* wu = (const float*)d_in[7];
  const float* wd = (const float*)d_in[8];
  float* out = (float*)d_out;
  char* ws = (char*)d_ws;

  __bf16* xb  = (__bf16*)(ws + 0);            //  8,388,608
  __bf16* hs  = (__bf16*)(ws + 8388608);      // 16,777,216
  __bf16* hr  = (__bf16*)(ws + 25165824);     // 33,554,432
  float*  y   = (float*)(ws + 58720256);      // 33,554,432
  __bf16* wgb = (__bf16*)(ws + 92274688);     // 33,554,432
  __bf16* wub = (__bf16*)(ws + 125829120);    // 33,554,432
  __bf16* wdb = (__bf16*)(ws + 159383552);    // 33,554,432
  __bf16* sgb = (__bf16*)(ws + 192937984);    //  4,194,304
  __bf16* sub = (__bf16*)(ws + 197132288);    //  4,194,304
  __bf16* sdb = (__bf16*)(ws + 201326592);    //  4,194,304
  int* counts = (int*)(ws + 205520896);
  int* list   = (int*)(ws + 205520960);       // 131,072
  int* tE     = (int*)(ws + 205652032);       // 32,768
  int* tP     = (int*)(ws + 205684800);       // 32,768
  float* tG   = (float*)(ws + 205717568);     // 32,768

  // prep: wg/wu/sg/su cast + router scoring (no atomics)
  k_prep<<<NBW + NBS + NT / 4, 256, 0, stream>>>(
      wg, wu, sg_w, su_w, wgb, wub, sgb, sub,
      x, router_w, routing_bias, xb, tE, tG);
  // slot assignment via LDS histogram (writes counts/list/tP)
  k_sched<<<1, 1024, 0, stream>>>(tE, counts, list, tP);
  // upgate GEMM (z<9) + wd/sd cast riding along (z in [9,18))
  dim3 gu(I_DIM / 64, NT / 128, (NE + 1) + 9);
  k_upgate97<<<gu, 256, 0, stream>>>(xb, wgb, wub, sgb, sub, counts, list,
                                     hs, hr, wd, sd_w, wdb, sdb);
  dim3 gd(H_DIM / 128, NT / 128, NE + 1);
  k_down97<<<gd, 256, 0, stream>>>(hs, hr, wdb, sdb, counts, out, y);
  k_combine<<<NT, 256, 0, stream>>>(y, counts, tE, tP, tG, out);
}